// Round 10
// baseline (301.847 us; speedup 1.0000x reference)
//
#include <hip/hip_runtime.h>
#include <hip/hip_bf16.h>

typedef unsigned short ushort_t;
typedef __attribute__((ext_vector_type(8))) short s8;     // 8 bf16 (4 VGPRs)
typedef __attribute__((ext_vector_type(4))) float f4;     // 16x16 MFMA C/D

__device__ __forceinline__ unsigned short f2bf(float f) {
  union { float f; unsigned int u; } c; c.f = f;
  unsigned int r = (c.u + 0x7fffu + ((c.u >> 16) & 1u)) >> 16;
  return (unsigned short)r;
}
__device__ __forceinline__ float bf2f(ushort_t u) {
  union { unsigned int i; float f; } c; c.i = ((unsigned int)u) << 16; return c.f;
}
__device__ __forceinline__ uint4 pack8(float4 a, float4 b) {
  uint4 r;
  r.x = (unsigned)f2bf(a.x) | ((unsigned)f2bf(a.y) << 16);
  r.y = (unsigned)f2bf(a.z) | ((unsigned)f2bf(a.w) << 16);
  r.z = (unsigned)f2bf(b.x) | ((unsigned)f2bf(b.y) << 16);
  r.w = (unsigned)f2bf(b.z) | ((unsigned)f2bf(b.w) << 16);
  return r;
}
// global -> LDS DMA, 16B per lane, wave-uniform LDS base + lane*16
__device__ __forceinline__ void dma16(const ushort_t* g, const short* l) {
  __builtin_amdgcn_global_load_lds(
      (const __attribute__((address_space(1))) unsigned int*)g,
      (__attribute__((address_space(3))) unsigned int*)(unsigned long)l,
      16, 0, 0);
}

// ---------- all weight transposes in one launch: dst[n][k] = bf16(src[k][n]) ----------
__global__ __launch_bounds__(256) void k_wt_all(
    const float* __restrict__ enc_w, const float* __restrict__ wq,
    const float* __restrict__ wk, const float* __restrict__ wv,
    const float* __restrict__ bn_w,
    ushort_t* __restrict__ enc_wT, ushort_t* __restrict__ wqkvT,
    ushort_t* __restrict__ bn_wT) {
  const int y = blockIdx.y;
  const int i = blockIdx.x * 256 + threadIdx.x;
  if (y == 0) {
    if (i < 131072) { const int n = i >> 9, k = i & 511; enc_wT[i] = f2bf(enc_w[k * 256 + n]); }
  } else if (y <= 3) {
    if (i < 65536) {
      const int n = i >> 8, k = i & 255;
      const float* src = (y == 1) ? wq : (y == 2) ? wk : wv;
      wqkvT[(y - 1) * 65536 + i] = f2bf(src[k * 256 + n]);
    }
  } else {
    if (i < 32768) { const int n = i >> 8, k = i & 255; bn_wT[i] = f2bf(bn_w[k * 128 + n]); }
  }
}

// ------- encoder GEMM + LN + ReLU; 32-row blocks (grid 512) -------
__global__ __launch_bounds__(256, 3) void k_gemm_enc(
    const float* __restrict__ A, const ushort_t* __restrict__ WT,
    const float* __restrict__ bia, const float* __restrict__ g,
    const float* __restrict__ beta, ushort_t* __restrict__ out) {
  __shared__ short Al[32 * 72];
  __shared__ short Bl[256 * 72];
  __shared__ float red1[32][2], red2[32][2];
  const int t = threadIdx.x;
  const int wv = t >> 6, lane = t & 63, l16 = lane & 15, quad = lane >> 4;
  const int wm = wv >> 1, wn = wv & 1;
  const int row0 = blockIdx.x * 32;

  f4 acc[8];
#pragma unroll
  for (int nf = 0; nf < 8; ++nf) acc[nf] = (f4){0.f, 0.f, 0.f, 0.f};

  for (int k0 = 0; k0 < 512; k0 += 64) {
    __syncthreads();
    {
      const int r = t >> 3, c8 = t & 7;
      const float* src = &A[(size_t)(row0 + r) * 512 + k0 + c8 * 8];
      *(uint4*)&Al[r * 72 + c8 * 8] =
          pack8(*(const float4*)src, *(const float4*)(src + 4));
    }
#pragma unroll
    for (int i = 0; i < 8; ++i) {
      const int ch = t + i * 256;
      const int r = ch >> 3, c8 = ch & 7;
      *(uint4*)&Bl[r * 72 + c8 * 8] =
          *(const uint4*)&WT[(size_t)r * 512 + k0 + c8 * 8];
    }
    __syncthreads();
#pragma unroll
    for (int kc = 0; kc < 2; ++kc) {
      const s8 af = *(const s8*)&Al[(wm * 16 + l16) * 72 + kc * 32 + quad * 8];
#pragma unroll
      for (int nf = 0; nf < 8; ++nf) {
        const s8 bf = *(const s8*)&Bl[(wn * 128 + nf * 16 + l16) * 72 + kc * 32 + quad * 8];
        acc[nf] = __builtin_amdgcn_mfma_f32_16x16x32_bf16(af, bf, acc[nf], 0, 0, 0);
      }
    }
  }
  float bi[8], gg[8], bb[8];
#pragma unroll
  for (int nf = 0; nf < 8; ++nf) {
    const int col = wn * 128 + nf * 16 + l16;
    bi[nf] = bia[col]; gg[nf] = g[col]; bb[nf] = beta[col];
  }
  float s1[4] = {0.f, 0.f, 0.f, 0.f}, s2[4] = {0.f, 0.f, 0.f, 0.f};
#pragma unroll
  for (int nf = 0; nf < 8; ++nf)
#pragma unroll
    for (int r = 0; r < 4; ++r) {
      const float v = acc[nf][r] + bi[nf];
      acc[nf][r] = v;
      s1[r] += v; s2[r] += v * v;
    }
#pragma unroll
  for (int m = 1; m < 16; m <<= 1) {
#pragma unroll
    for (int r = 0; r < 4; ++r) {
      s1[r] += __shfl_xor(s1[r], m);
      s2[r] += __shfl_xor(s2[r], m);
    }
  }
  if (l16 == 0) {
#pragma unroll
    for (int r = 0; r < 4; ++r) {
      const int rl = wm * 16 + quad * 4 + r;
      red1[rl][wn] = s1[r]; red2[rl][wn] = s2[r];
    }
  }
  __syncthreads();
#pragma unroll
  for (int r = 0; r < 4; ++r) {
    const int rl = wm * 16 + quad * 4 + r;
    const float mu = (red1[rl][0] + red1[rl][1]) * (1.f / 256.f);
    const float var = (red2[rl][0] + red2[rl][1]) * (1.f / 256.f) - mu * mu;
    const float rstd = rsqrtf(var + 1e-5f);
#pragma unroll
    for (int nf = 0; nf < 8; ++nf) {
      const int col = wn * 128 + nf * 16 + l16;
      const float v = (acc[nf][r] - mu) * rstd * gg[nf] + bb[nf];
      out[(size_t)(row0 + rl) * 256 + col] = f2bf(fmaxf(v, 0.f));
    }
  }
}

// ---- QKV GEMM: A=h_bf, WT=wqkvT [768][256]; q scaled 1/16, v -> VT ----
__global__ __launch_bounds__(256, 4) void k_gemm_qkv(
    const ushort_t* __restrict__ A, const ushort_t* __restrict__ WT,
    const float* __restrict__ bq, const float* __restrict__ bk,
    const float* __restrict__ bv,
    ushort_t* __restrict__ q, ushort_t* __restrict__ k, ushort_t* __restrict__ vt) {
  __shared__ short Al[64 * 72];
  __shared__ short Bl[128 * 72];
  const int t = threadIdx.x;
  const int wv = t >> 6, lane = t & 63, l16 = lane & 15, quad = lane >> 4;
  const int wm = wv >> 1, wn = wv & 1;
  const int row0 = blockIdx.x * 64;
  const int nb = blockIdx.y;
  const int type = nb >> 1;
  const ushort_t* wtb = WT + (size_t)nb * 128 * 256;

  f4 acc[2][4];
#pragma unroll
  for (int mf = 0; mf < 2; ++mf)
#pragma unroll
    for (int nf = 0; nf < 4; ++nf) acc[mf][nf] = (f4){0.f, 0.f, 0.f, 0.f};

  for (int k0 = 0; k0 < 256; k0 += 64) {
    __syncthreads();
#pragma unroll
    for (int i = 0; i < 2; ++i) {
      const int ch = t + i * 256;
      const int r = ch >> 3, c8 = ch & 7;
      *(uint4*)&Al[r * 72 + c8 * 8] =
          *(const uint4*)&A[(size_t)(row0 + r) * 256 + k0 + c8 * 8];
    }
#pragma unroll
    for (int i = 0; i < 4; ++i) {
      const int ch = t + i * 256;
      const int r = ch >> 3, c8 = ch & 7;
      *(uint4*)&Bl[r * 72 + c8 * 8] =
          *(const uint4*)&wtb[(size_t)r * 256 + k0 + c8 * 8];
    }
    __syncthreads();
#pragma unroll
    for (int kc = 0; kc < 2; ++kc) {
      s8 af[2];
      af[0] = *(const s8*)&Al[(wm * 32 + l16) * 72 + kc * 32 + quad * 8];
      af[1] = *(const s8*)&Al[(wm * 32 + 16 + l16) * 72 + kc * 32 + quad * 8];
#pragma unroll
      for (int nf = 0; nf < 4; ++nf) {
        const s8 bf = *(const s8*)&Bl[(wn * 64 + nf * 16 + l16) * 72 + kc * 32 + quad * 8];
        acc[0][nf] = __builtin_amdgcn_mfma_f32_16x16x32_bf16(af[0], bf, acc[0][nf], 0, 0, 0);
        acc[1][nf] = __builtin_amdgcn_mfma_f32_16x16x32_bf16(af[1], bf, acc[1][nf], 0, 0, 0);
      }
    }
  }
  const float* bias = (type == 0) ? bq : (type == 1) ? bk : bv;
#pragma unroll
  for (int nf = 0; nf < 4; ++nf) {
    const int colg = nb * 128 + wn * 64 + nf * 16 + l16;
    const int col = colg - type * 256;
    const float bi = bias[col];
    if (type == 2) {
      const int b = row0 >> 11;
#pragma unroll
      for (int mf = 0; mf < 2; ++mf) {
        const int n = (row0 & 2047) + wm * 32 + mf * 16 + quad * 4;
        ushort4 pk;
        pk.x = f2bf(acc[mf][nf][0] + bi);
        pk.y = f2bf(acc[mf][nf][1] + bi);
        pk.z = f2bf(acc[mf][nf][2] + bi);
        pk.w = f2bf(acc[mf][nf][3] + bi);
        *(ushort4*)&vt[((size_t)b * 256 + col) * 2048 + n] = pk;
      }
    } else {
      ushort_t* dst = (type == 0) ? q : k;
      const float sc = (type == 0) ? 0.0625f : 1.f;
#pragma unroll
      for (int mf = 0; mf < 2; ++mf)
#pragma unroll
        for (int r = 0; r < 4; ++r) {
          const int row = row0 + wm * 32 + mf * 16 + quad * 4 + r;
          dst[(size_t)row * 256 + col] = f2bf((acc[mf][nf][r] + bi) * sc);
        }
    }
  }
}

// ---- MFMA flash attention v8: 16q/wave for occupancy; 16-key DMA tiles ----
// grid (32 qtiles x64q, 4 ks x512keys, 8 batch), 256 thr = 4 waves x 16 q
// LDS 37 KB; per-wave regs ~140 -> 3 waves/SIMD -> 3 blocks/CU (12 waves).
// K LDS: [d-chunk:32][key:16][8 shorts of d] (DMA-linear, frag-contiguous)
// V LDS: [d:256][key:16] (DMA-linear; PV B-frag = 8 contiguous keys)
// PV uses 16x16x32 with pl cols 16..31 zeroed once (A-frag quads 2,3 = 0).
__global__ __launch_bounds__(256, 3) void k_attn(
    const ushort_t* __restrict__ qb, const ushort_t* __restrict__ kb,
    const ushort_t* __restrict__ vtb,
    const float* __restrict__ coords, const int* __restrict__ mask,
    const float* __restrict__ gam,
    ushort_t* __restrict__ Opb, float* __restrict__ lws) {
  __shared__ short kld[2][4096];   // 2 x 8 KB
  __shared__ short vld[2][4096];   // 2 x 8 KB
  __shared__ short pl[64 * 40];    // 5 KB; cols 16..31 stay zero
  const int t = threadIdx.x;
  const int wv = t >> 6, lane = t & 63, l16 = lane & 15, quad = lane >> 4;
  const int b = blockIdx.z, ks = blockIdx.y;
  const int qw = blockIdx.x * 64 + wv * 16;
  const int kbase = ks * 512;

  // zero the PV A-frag pad (cols 16..31) once
  {
    unsigned int* z = (unsigned int*)&pl[(t >> 2) * 40 + 16 + (t & 3) * 4];
    z[0] = 0u; z[1] = 0u;
  }

  float rcx[4], rcy[4];
#pragma unroll
  for (int r = 0; r < 4; ++r) {
    const float2 cc = ((const float2*)coords)[b * 2048 + qw + quad * 4 + r];
    rcx[r] = cc.x; rcy[r] = cc.y;
  }
  const float gamma = fabsf(gam[0]);

  f4 o16[16];
#pragma unroll
  for (int i = 0; i < 16; ++i) o16[i] = (f4){0.f, 0.f, 0.f, 0.f};
  float lrun[4] = {0.f, 0.f, 0.f, 0.f};

  const ushort_t* kbb = kb + ((size_t)b * 2048 + kbase) * 256;
  const ushort_t* vbb = vtb + (size_t)b * 256 * 2048 + kbase;
  const ushort_t* qrow = qb + ((size_t)b * 2048 + qw + l16) * 256 + quad * 8;

  // stage tile 0 (K: 2 instr/wave, V: 2 instr/wave)
#pragma unroll
  for (int i = 0; i < 2; ++i) {
    const int i2 = wv * 2 + i;
    dma16(kbb + (size_t)(lane & 15) * 256 + (i2 * 4 + (lane >> 4)) * 8,
          &kld[0][i2 * 512]);
    dma16(vbb + (size_t)(i2 * 32 + (lane >> 1)) * 2048 + (lane & 1) * 8,
          &vld[0][i2 * 512]);
  }
  __syncthreads();

  for (int kt = 0; kt < 32; ++kt) {
    const int cur = kt & 1;
    const int m0 = kbase + kt * 16;
    if (kt < 31) {                     // DMA next 16-key tile into idle buffer
      const ushort_t* kn = kbb + (size_t)(kt + 1) * 16 * 256;
      const ushort_t* vn = vbb + (kt + 1) * 16;
      const int nb2 = cur ^ 1;
#pragma unroll
      for (int i = 0; i < 2; ++i) {
        const int i2 = wv * 2 + i;
        dma16(kn + (size_t)(lane & 15) * 256 + (i2 * 4 + (lane >> 4)) * 8,
              &kld[nb2][i2 * 512]);
        dma16(vn + (size_t)(i2 * 32 + (lane >> 1)) * 2048 + (lane & 1) * 8,
              &vld[nb2][i2 * 512]);
      }
    }
    // QK^T: S[16q x 16k] = one frag; 8 chunks over D=256
    f4 sc = (f4){0.f, 0.f, 0.f, 0.f};
#pragma unroll
    for (int c = 0; c < 8; ++c) {
      const s8 qa = *(const s8*)(qrow + c * 32);    // L1-resident reload
      const s8 bfr = *(const s8*)&kld[cur][((c * 4 + quad) * 16 + l16) * 8];
      sc = __builtin_amdgcn_mfma_f32_16x16x32_bf16(qa, bfr, sc, 0, 0, 0);
    }
    // exp (no max-shift), l partials, weights -> pl cols 0..15
    {
      const int m = m0 + l16;
      const float2 cc = ((const float2*)coords)[b * 2048 + m];
      const float mfv = mask[b * 2048 + m] ? 0.f : 1.f;
#pragma unroll
      for (int r = 0; r < 4; ++r) {
        const float p = __expf(sc[r]);
        lrun[r] += p;
        const float dx = rcx[r] - cc.x, dy = rcy[r] - cc.y;
        const float dist = sqrtf(fmaxf(dx * dx + dy * dy, 0.f));
        const float w = p * __expf(-gamma * dist) * mfv;
        pl[(wv * 16 + quad * 4 + r) * 40 + l16] = (short)f2bf(w);
      }
    }
    // PV: O[16q x 256d] += P[16q x 16k(+16 zero)] * V
    const s8 pa = *(const s8*)&pl[(wv * 16 + l16) * 40 + quad * 8];  // quads 2,3 read zeros
#pragma unroll
    for (int df = 0; df < 16; ++df) {
      // quads 2,3: A=0, B value irrelevant -> reuse quad&1 address (in-bounds, broadcast)
      const s8 bv = *(const s8*)&vld[cur][((df * 16 + l16) * 16) + (quad & 1) * 8];
      o16[df] = __builtin_amdgcn_mfma_f32_16x16x32_bf16(pa, bv, o16[df], 0, 0, 0);
    }
    __syncthreads();
  }
  // epilogue: partial O (unnormalized, bf16), 16x16 C-layout
  ushort_t* OpK = Opb + (size_t)ks * 4194304;
#pragma unroll
  for (int r = 0; r < 4; ++r) {
    ushort_t* orow = OpK + ((size_t)b * 2048 + qw + quad * 4 + r) * 256 + l16;
#pragma unroll
    for (int df = 0; df < 16; ++df) orow[df * 16] = f2bf(o16[df][r]);
  }
  // l: one end-of-kernel reduction across the 16 key-lanes
#pragma unroll
  for (int o2 = 1; o2 < 16; o2 <<= 1) {
#pragma unroll
    for (int r = 0; r < 4; ++r) lrun[r] += __shfl_xor(lrun[r], o2);
  }
  if (l16 == 0) {
#pragma unroll
    for (int r = 0; r < 4; ++r)
      lws[ks * 16384 + b * 2048 + qw + quad * 4 + r] = lrun[r];
  }
}

// ---- BN GEMM + LN + ReLU, fused 4-way merge: agg = sum(Op_p)/sum(l_p) ----
__global__ __launch_bounds__(256, 3) void k_gemm_bn(
    const ushort_t* __restrict__ Opb, const float* __restrict__ lws,
    const ushort_t* __restrict__ WT,
    const float* __restrict__ bia, const float* __restrict__ g,
    const float* __restrict__ beta, ushort_t* __restrict__ out) {
  __shared__ short Al[32 * 72];
  __shared__ short Bl[128 * 72];
  __shared__ float red1[32][2], red2[32][2];
  __shared__ float sCm[32];
  const int t = threadIdx.x;
  const int wv = t >> 6, lane = t & 63, l16 = lane & 15, quad = lane >> 4;
  const int wm = wv >> 1, wn = wv & 1;
  const int row0 = blockIdx.x * 32;

  if (t < 32) {
    const int row = row0 + t;
    sCm[t] = 1.f / (lws[row] + lws[16384 + row] + lws[32768 + row] + lws[49152 + row]);
  }

  f4 acc[4];
#pragma unroll
  for (int nf = 0; nf < 4; ++nf) acc[nf] = (f4){0.f, 0.f, 0.f, 0.f};

  for (int k0 = 0; k0 < 256; k0 += 64) {
    __syncthreads();
    {   // stage A: sum 4 bf16 partials, scale, repack bf16
      const int r = t >> 3, c8 = t & 7;
      const float c0 = sCm[r];
      const size_t off = (size_t)(row0 + r) * 256 + k0 + c8 * 8;
      float e[8];
#pragma unroll
      for (int j = 0; j < 8; ++j) e[j] = 0.f;
#pragma unroll
      for (int pp = 0; pp < 4; ++pp) {
        const uint4 u = *(const uint4*)&Opb[(size_t)pp * 4194304 + off];
        e[0] += bf2f((ushort_t)(u.x & 0xffff)); e[1] += bf2f((ushort_t)(u.x >> 16));
        e[2] += bf2f((ushort_t)(u.y & 0xffff)); e[3] += bf2f((ushort_t)(u.y >> 16));
        e[4] += bf2f((ushort_t)(u.z & 0xffff)); e[5] += bf2f((ushort_t)(u.z >> 16));
        e[6] += bf2f((ushort_t)(u.w & 0xffff)); e[7] += bf2f((ushort_t)(u.w >> 16));
      }
      float4 ea = {c0 * e[0], c0 * e[1], c0 * e[2], c0 * e[3]};
      float4 eb = {c0 * e[4], c0 * e[5], c0 * e[6], c0 * e[7]};
      *(uint4*)&Al[r * 72 + c8 * 8] = pack8(ea, eb);
    }
#pragma unroll
    for (int i = 0; i < 4; ++i) {
      const int ch = t + i * 256;
      const int r = ch >> 3, c8 = ch & 7;
      *(uint4*)&Bl[r * 72 + c8 * 8] =
          *(const uint4*)&WT[(size_t)r * 256 + k0 + c8 * 8];
    }
    __syncthreads();
#pragma unroll
    for (int kc = 0; kc < 2; ++kc) {
      const s8 af = *(const s8*)&Al[(wm * 16 + l16) * 72 + kc * 32 + quad * 8];
#pragma unroll
      for (int nf = 0; nf < 4; ++nf) {
        const s8 bf = *(const s8*)&Bl[(wn * 64 + nf * 16 + l16) * 72 + kc * 32 + quad * 8];
        acc[nf] = __builtin_amdgcn_mfma_f32_16x16x32_bf16(af, bf, acc[nf], 0, 0, 0);
      }
    }
  }
  float bi[4], gg[4], bb[4];
#pragma unroll
  for (int nf = 0; nf < 4; ++nf) {
    const int col = wn * 64 + nf * 16 + l16;
    bi[nf] = bia[col]; gg[nf] = g[col]; bb[nf] = beta[col];
  }
  float s1[4] = {0.f, 0.f, 0.f, 0.f}, s2[4] = {0.f, 0.f, 0.f, 0.f};
#pragma unroll
  for (int nf = 0; nf < 4; ++nf)
#pragma unroll
    for (int r = 0; r < 4; ++r) {
      const float v = acc[nf][r] + bi[nf];
      acc[nf][r] = v;
      s1[r] += v; s2[r] += v * v;
    }
#pragma unroll
  for (int m = 1; m < 16; m <<= 1) {
#pragma unroll
    for (int r = 0; r < 4; ++r) {
      s1[r] += __shfl_xor(s1[r], m);
      s2[r] += __shfl_xor(s2[r], m);
    }
  }
  if (l16 == 0) {
#pragma unroll
    for (int r = 0; r < 4; ++r) {
      const int rl = wm * 16 + quad * 4 + r;
      red1[rl][wn] = s1[r]; red2[rl][wn] = s2[r];
    }
  }
  __syncthreads();
#pragma unroll
  for (int r = 0; r < 4; ++r) {
    const int rl = wm * 16 + quad * 4 + r;
    const float mu = (red1[rl][0] + red1[rl][1]) * (1.f / 128.f);
    const float var = (red2[rl][0] + red2[rl][1]) * (1.f / 128.f) - mu * mu;
    const float rstd = rsqrtf(var + 1e-5f);
#pragma unroll
    for (int nf = 0; nf < 4; ++nf) {
      const int col = wn * 64 + nf * 16 + l16;
      const float v = (acc[nf][r] - mu) * rstd * gg[nf] + bb[nf];
      out[(size_t)(row0 + rl) * 128 + col] = f2bf(fmaxf(v, 0.f));
    }
  }
}

// ---------------- masked mean pool stage 1 ----------------
__global__ __launch_bounds__(128) void k_pool1(
    const ushort_t* __restrict__ obn, const int* __restrict__ mask,
    float* __restrict__ pp) {
  const int g = blockIdx.x, b = blockIdx.y, d = threadIdx.x;
  const ushort_t* ob = obn + ((size_t)b * 2048 + g * 128) * 128;
  const int* mb = mask + b * 2048 + g * 128;
  float s = 0.f, cnt = 0.f;
  for (int n = 0; n < 128; ++n) {
    const float w = mb[n] ? 0.f : 1.f;
    s += w * bf2f(ob[(size_t)n * 128 + d]);
    cnt += w;
  }
  pp[(b * 16 + g) * 132 + d] = s;
  if (d == 0) pp[(b * 16 + g) * 132 + 128] = cnt;
}

// ---------------- fused pool stage 2 + MLP head ----------------
__global__ __launch_bounds__(128) void k_pool2_head(
    const float* __restrict__ pp, const float* __restrict__ c1w,
    const float* __restrict__ c1b, const float* __restrict__ c2w,
    const float* __restrict__ c2b, float* __restrict__ dout) {
  __shared__ float ps[128];
  __shared__ float h1[64];
  const int b = blockIdx.x, t = threadIdx.x;
  float s = 0.f, cnt = 0.f;
  for (int g = 0; g < 16; ++g) {
    s += pp[(b * 16 + g) * 132 + t];
    cnt += pp[(b * 16 + g) * 132 + 128];
  }
  const float p = s / fmaxf(cnt, 1e-9f);
  ps[t] = p;
  dout[80 + b * 128 + t] = p;
  __syncthreads();
  if (t < 64) {
    float acc = c1b[t];
    for (int d = 0; d < 128; ++d) acc += ps[d] * c1w[d * 64 + t];
    h1[t] = fmaxf(acc, 0.f);
  }
  __syncthreads();
  if (t < 10) {
    float a2 = c2b[t];
    for (int j = 0; j < 64; ++j) a2 += h1[j] * c2w[j * 10 + t];
    dout[b * 10 + t] = a2;
  }
}

extern "C" void kernel_launch(void* const* d_in, const int* in_sizes, int n_in,
                              void* d_out, int out_size, void* d_ws, size_t ws_size,
                              hipStream_t stream) {
  const float* lf     = (const float*)d_in[0];
  const float* coords = (const float*)d_in[1];
  const int*   mask   = (const int*)d_in[2];
  const float* enc_w  = (const float*)d_in[3];
  const float* enc_b  = (const float*)d_in[4];
  const float* enc_g  = (const float*)d_in[5];
  const float* enc_be = (const float*)d_in[6];
  const float* gamma  = (const float*)d_in[7];
  const float* wq     = (const float*)d_in[8];
  const float* bq     = (const float*)d_in[9];
  const float* wk     = (const float*)d_in[10];
  const float* bk     = (const float*)d_in[11];
  const float* wv     = (const float*)d_in[12];
  const float* bv     = (const float*)d_in[13];
  const float* bn_w   = (const float*)d_in[14];
  const float* bn_b   = (const float*)d_in[15];
  const float* bn_g   = (const float*)d_in[16];
  const float* bn_be  = (const float*)d_in[17];
  const float* c1w    = (const float*)d_in[18];
  const float* c1b    = (const float*)d_in[19];
  const float* c2w    = (const float*)d_in[20];
  const float* c2b    = (const float*)d_in[21];

  // ws layout (float units), ~73 MB (same as R9)
  float* ws = (float*)d_ws;
  ushort_t* h_bf   = (ushort_t*)ws;
  ushort_t* q_bf   = (ushort_t*)(ws + 2097152);
  ushort_t* k_bf   = (ushort_t*)(ws + 4194304);
  ushort_t* vt_bf  = (ushort_t*)(ws + 6291456);
  ushort_t* Opb    = (ushort_t*)(ws + 8388608);    // 4 x 4194304 ushorts
  ushort_t* obn_bf = (ushort_t*)(ws + 16777216);
  ushort_t* enc_wT = (ushort_t*)(ws + 17825792);
  ushort_t* wqkvT  = (ushort_t*)(ws + 17891328);
  ushort_t* bn_wT  = (ushort_t*)(ws + 17989632);
  float*    lws    = ws + 18006016;                // 4 x 16384
  float*    ppart  = ws + 18071552;
  float* out = (float*)d_out;

  k_wt_all<<<dim3(512, 5), 256, 0, stream>>>(enc_w, wq, wk, wv, bn_w,
                                             enc_wT, wqkvT, bn_wT);
  k_gemm_enc<<<512, 256, 0, stream>>>(lf, enc_wT, enc_b, enc_g, enc_be, h_bf);
  k_gemm_qkv<<<dim3(256, 6), 256, 0, stream>>>(h_bf, wqkvT, bq, bk, bv, q_bf, k_bf, vt_bf);
  k_attn<<<dim3(32, 4, 8), 256, 0, stream>>>(q_bf, k_bf, vt_bf, coords, mask, gamma,
                                             Opb, lws);
  k_gemm_bn<<<512, 256, 0, stream>>>(Opb, lws, bn_wT, bn_b, bn_g, bn_be, obn_bf);
  k_pool1<<<dim3(16, 8), 128, 0, stream>>>(obn_bf, mask, ppart);
  k_pool2_head<<<8, 128, 0, stream>>>(ppart, c1w, c1b, c2w, c2b, out);
}

// Round 11
// 258.668 us; speedup vs baseline: 1.1669x; 1.1669x over previous
//
#include <hip/hip_runtime.h>
#include <hip/hip_bf16.h>

typedef unsigned short ushort_t;
typedef __attribute__((ext_vector_type(8))) short s8;     // 8 bf16 (4 VGPRs)
typedef __attribute__((ext_vector_type(4))) float f4;     // 16x16 MFMA C/D
typedef __attribute__((ext_vector_type(16))) float f16v;  // 32x32 MFMA C/D

__device__ __forceinline__ unsigned short f2bf(float f) {
  union { float f; unsigned int u; } c; c.f = f;
  unsigned int r = (c.u + 0x7fffu + ((c.u >> 16) & 1u)) >> 16;
  return (unsigned short)r;
}
__device__ __forceinline__ float bf2f(ushort_t u) {
  union { unsigned int i; float f; } c; c.i = ((unsigned int)u) << 16; return c.f;
}
__device__ __forceinline__ uint4 pack8(float4 a, float4 b) {
  uint4 r;
  r.x = (unsigned)f2bf(a.x) | ((unsigned)f2bf(a.y) << 16);
  r.y = (unsigned)f2bf(a.z) | ((unsigned)f2bf(a.w) << 16);
  r.z = (unsigned)f2bf(b.x) | ((unsigned)f2bf(b.y) << 16);
  r.w = (unsigned)f2bf(b.z) | ((unsigned)f2bf(b.w) << 16);
  return r;
}
// global -> LDS DMA, 16B per lane, wave-uniform LDS base + lane*16
__device__ __forceinline__ void dma16(const ushort_t* g, const short* l) {
  __builtin_amdgcn_global_load_lds(
      (const __attribute__((address_space(1))) unsigned int*)g,
      (__attribute__((address_space(3))) unsigned int*)(unsigned long)l,
      16, 0, 0);
}

// ---------- all weight transposes in one launch: dst[n][k] = bf16(src[k][n]) ----------
__global__ __launch_bounds__(256) void k_wt_all(
    const float* __restrict__ enc_w, const float* __restrict__ wq,
    const float* __restrict__ wk, const float* __restrict__ wv,
    const float* __restrict__ bn_w,
    ushort_t* __restrict__ enc_wT, ushort_t* __restrict__ wqkvT,
    ushort_t* __restrict__ bn_wT) {
  const int y = blockIdx.y;
  const int i = blockIdx.x * 256 + threadIdx.x;
  if (y == 0) {
    if (i < 131072) { const int n = i >> 9, k = i & 511; enc_wT[i] = f2bf(enc_w[k * 256 + n]); }
  } else if (y <= 3) {
    if (i < 65536) {
      const int n = i >> 8, k = i & 255;
      const float* src = (y == 1) ? wq : (y == 2) ? wk : wv;
      wqkvT[(y - 1) * 65536 + i] = f2bf(src[k * 256 + n]);
    }
  } else {
    if (i < 32768) { const int n = i >> 8, k = i & 255; bn_wT[i] = f2bf(bn_w[k * 128 + n]); }
  }
}

// ------- encoder GEMM + LN + ReLU; 32-row blocks (grid 512) -------
__global__ __launch_bounds__(256, 3) void k_gemm_enc(
    const float* __restrict__ A, const ushort_t* __restrict__ WT,
    const float* __restrict__ bia, const float* __restrict__ g,
    const float* __restrict__ beta, ushort_t* __restrict__ out) {
  __shared__ short Al[32 * 72];
  __shared__ short Bl[256 * 72];
  __shared__ float red1[32][2], red2[32][2];
  const int t = threadIdx.x;
  const int wv = t >> 6, lane = t & 63, l16 = lane & 15, quad = lane >> 4;
  const int wm = wv >> 1, wn = wv & 1;
  const int row0 = blockIdx.x * 32;

  f4 acc[8];
#pragma unroll
  for (int nf = 0; nf < 8; ++nf) acc[nf] = (f4){0.f, 0.f, 0.f, 0.f};

  for (int k0 = 0; k0 < 512; k0 += 64) {
    __syncthreads();
    {
      const int r = t >> 3, c8 = t & 7;
      const float* src = &A[(size_t)(row0 + r) * 512 + k0 + c8 * 8];
      *(uint4*)&Al[r * 72 + c8 * 8] =
          pack8(*(const float4*)src, *(const float4*)(src + 4));
    }
#pragma unroll
    for (int i = 0; i < 8; ++i) {
      const int ch = t + i * 256;
      const int r = ch >> 3, c8 = ch & 7;
      *(uint4*)&Bl[r * 72 + c8 * 8] =
          *(const uint4*)&WT[(size_t)r * 512 + k0 + c8 * 8];
    }
    __syncthreads();
#pragma unroll
    for (int kc = 0; kc < 2; ++kc) {
      const s8 af = *(const s8*)&Al[(wm * 16 + l16) * 72 + kc * 32 + quad * 8];
#pragma unroll
      for (int nf = 0; nf < 8; ++nf) {
        const s8 bf = *(const s8*)&Bl[(wn * 128 + nf * 16 + l16) * 72 + kc * 32 + quad * 8];
        acc[nf] = __builtin_amdgcn_mfma_f32_16x16x32_bf16(af, bf, acc[nf], 0, 0, 0);
      }
    }
  }
  float bi[8], gg[8], bb[8];
#pragma unroll
  for (int nf = 0; nf < 8; ++nf) {
    const int col = wn * 128 + nf * 16 + l16;
    bi[nf] = bia[col]; gg[nf] = g[col]; bb[nf] = beta[col];
  }
  float s1[4] = {0.f, 0.f, 0.f, 0.f}, s2[4] = {0.f, 0.f, 0.f, 0.f};
#pragma unroll
  for (int nf = 0; nf < 8; ++nf)
#pragma unroll
    for (int r = 0; r < 4; ++r) {
      const float v = acc[nf][r] + bi[nf];
      acc[nf][r] = v;
      s1[r] += v; s2[r] += v * v;
    }
#pragma unroll
  for (int m = 1; m < 16; m <<= 1) {
#pragma unroll
    for (int r = 0; r < 4; ++r) {
      s1[r] += __shfl_xor(s1[r], m);
      s2[r] += __shfl_xor(s2[r], m);
    }
  }
  if (l16 == 0) {
#pragma unroll
    for (int r = 0; r < 4; ++r) {
      const int rl = wm * 16 + quad * 4 + r;
      red1[rl][wn] = s1[r]; red2[rl][wn] = s2[r];
    }
  }
  __syncthreads();
#pragma unroll
  for (int r = 0; r < 4; ++r) {
    const int rl = wm * 16 + quad * 4 + r;
    const float mu = (red1[rl][0] + red1[rl][1]) * (1.f / 256.f);
    const float var = (red2[rl][0] + red2[rl][1]) * (1.f / 256.f) - mu * mu;
    const float rstd = rsqrtf(var + 1e-5f);
#pragma unroll
    for (int nf = 0; nf < 8; ++nf) {
      const int col = wn * 128 + nf * 16 + l16;
      const float v = (acc[nf][r] - mu) * rstd * gg[nf] + bb[nf];
      out[(size_t)(row0 + rl) * 256 + col] = f2bf(fmaxf(v, 0.f));
    }
  }
}

// ---- QKV GEMM: A=h_bf, WT=wqkvT [768][256]; q scaled 1/16, v -> VT ----
__global__ __launch_bounds__(256, 4) void k_gemm_qkv(
    const ushort_t* __restrict__ A, const ushort_t* __restrict__ WT,
    const float* __restrict__ bq, const float* __restrict__ bk,
    const float* __restrict__ bv,
    ushort_t* __restrict__ q, ushort_t* __restrict__ k, ushort_t* __restrict__ vt) {
  __shared__ short Al[64 * 72];
  __shared__ short Bl[128 * 72];
  const int t = threadIdx.x;
  const int wv = t >> 6, lane = t & 63, l16 = lane & 15, quad = lane >> 4;
  const int wm = wv >> 1, wn = wv & 1;
  const int row0 = blockIdx.x * 64;
  const int nb = blockIdx.y;
  const int type = nb >> 1;
  const ushort_t* wtb = WT + (size_t)nb * 128 * 256;

  f4 acc[2][4];
#pragma unroll
  for (int mf = 0; mf < 2; ++mf)
#pragma unroll
    for (int nf = 0; nf < 4; ++nf) acc[mf][nf] = (f4){0.f, 0.f, 0.f, 0.f};

  for (int k0 = 0; k0 < 256; k0 += 64) {
    __syncthreads();
#pragma unroll
    for (int i = 0; i < 2; ++i) {
      const int ch = t + i * 256;
      const int r = ch >> 3, c8 = ch & 7;
      *(uint4*)&Al[r * 72 + c8 * 8] =
          *(const uint4*)&A[(size_t)(row0 + r) * 256 + k0 + c8 * 8];
    }
#pragma unroll
    for (int i = 0; i < 4; ++i) {
      const int ch = t + i * 256;
      const int r = ch >> 3, c8 = ch & 7;
      *(uint4*)&Bl[r * 72 + c8 * 8] =
          *(const uint4*)&wtb[(size_t)r * 256 + k0 + c8 * 8];
    }
    __syncthreads();
#pragma unroll
    for (int kc = 0; kc < 2; ++kc) {
      s8 af[2];
      af[0] = *(const s8*)&Al[(wm * 32 + l16) * 72 + kc * 32 + quad * 8];
      af[1] = *(const s8*)&Al[(wm * 32 + 16 + l16) * 72 + kc * 32 + quad * 8];
#pragma unroll
      for (int nf = 0; nf < 4; ++nf) {
        const s8 bf = *(const s8*)&Bl[(wn * 64 + nf * 16 + l16) * 72 + kc * 32 + quad * 8];
        acc[0][nf] = __builtin_amdgcn_mfma_f32_16x16x32_bf16(af[0], bf, acc[0][nf], 0, 0, 0);
        acc[1][nf] = __builtin_amdgcn_mfma_f32_16x16x32_bf16(af[1], bf, acc[1][nf], 0, 0, 0);
      }
    }
  }
  const float* bias = (type == 0) ? bq : (type == 1) ? bk : bv;
#pragma unroll
  for (int nf = 0; nf < 4; ++nf) {
    const int colg = nb * 128 + wn * 64 + nf * 16 + l16;
    const int col = colg - type * 256;
    const float bi = bias[col];
    if (type == 2) {
      const int b = row0 >> 11;
#pragma unroll
      for (int mf = 0; mf < 2; ++mf) {
        const int n = (row0 & 2047) + wm * 32 + mf * 16 + quad * 4;
        ushort4 pk;
        pk.x = f2bf(acc[mf][nf][0] + bi);
        pk.y = f2bf(acc[mf][nf][1] + bi);
        pk.z = f2bf(acc[mf][nf][2] + bi);
        pk.w = f2bf(acc[mf][nf][3] + bi);
        *(ushort4*)&vt[((size_t)b * 256 + col) * 2048 + n] = pk;
      }
    } else {
      ushort_t* dst = (type == 0) ? q : k;
      const float sc = (type == 0) ? 0.0625f : 1.f;
#pragma unroll
      for (int mf = 0; mf < 2; ++mf)
#pragma unroll
        for (int r = 0; r < 4; ++r) {
          const int row = row0 + wm * 32 + mf * 16 + quad * 4 + r;
          dst[(size_t)row * 256 + col] = f2bf((acc[mf][nf][r] + bi) * sc);
        }
    }
  }
}

// ---- MFMA flash attention (R9-proven): QK 16x16x32, PV 32x32x16, DMA dbuf, no-max ----
// grid (16 qtiles x128, 4 ks x512keys, 8 batch), 256 thr = 4 waves x 32 q
// 16 tiles of 32 keys; LDS 74 KB -> 2 blocks/CU; one barrier per tile.
__global__ __launch_bounds__(256, 2) void k_attn(
    const ushort_t* __restrict__ qb, const ushort_t* __restrict__ kb,
    const ushort_t* __restrict__ vtb,
    const float* __restrict__ coords, const int* __restrict__ mask,
    const float* __restrict__ gam,
    ushort_t* __restrict__ Opb, float* __restrict__ lws) {
  __shared__ short kld[2][8192];   // 2 x 16 KB, [d-chunk:32][key:32][8]
  __shared__ short vld[2][8192];   // 2 x 16 KB, [m-chunk:4][d:256][8]
  __shared__ short pl[128 * 40];   // 10 KB
  const int t = threadIdx.x;
  const int wv = t >> 6, lane = t & 63, l16 = lane & 15, quad = lane >> 4;
  const int hw = lane >> 5, l32 = lane & 31;
  const int b = blockIdx.z, ks = blockIdx.y;
  const int qw = blockIdx.x * 128 + wv * 32;
  const int kbase = ks * 512;

  float rcx[2][4], rcy[2][4];
#pragma unroll
  for (int mf = 0; mf < 2; ++mf)
#pragma unroll
    for (int r = 0; r < 4; ++r) {
      const float2 cc = ((const float2*)coords)[b * 2048 + qw + mf * 16 + quad * 4 + r];
      rcx[mf][r] = cc.x; rcy[mf][r] = cc.y;
    }
  const float gamma = fabsf(gam[0]);

  f16v o32[8];
#pragma unroll
  for (int i = 0; i < 8; ++i)
#pragma unroll
    for (int j = 0; j < 16; ++j) o32[i][j] = 0.f;
  float lrun[2][4];
#pragma unroll
  for (int mf = 0; mf < 2; ++mf)
#pragma unroll
    for (int r = 0; r < 4; ++r) lrun[mf][r] = 0.f;

  const ushort_t* kbb = kb + ((size_t)b * 2048 + kbase) * 256;
  const ushort_t* vbb = vtb + (size_t)b * 256 * 2048 + kbase;
  const ushort_t* qrow0 = qb + ((size_t)b * 2048 + qw + l16) * 256 + quad * 8;
  const ushort_t* qrow1 = qrow0 + 16 * 256;

  // stage tile 0 into buffer 0
#pragma unroll
  for (int i = 0; i < 4; ++i) {
    const int i2 = wv * 4 + i;
    dma16(kbb + (size_t)l32 * 256 + (i2 * 2 + hw) * 8, &kld[0][i2 * 512]);
    dma16(vbb + (size_t)(i * 64 + lane) * 2048 + wv * 8, &vld[0][(wv * 256 + i * 64) * 8]);
  }
  __syncthreads();

  for (int kt = 0; kt < 16; ++kt) {
    const int cur = kt & 1;
    const int m0 = kbase + kt * 32;
    if (kt < 15) {                     // DMA next tile into idle buffer
      const ushort_t* kn = kbb + (size_t)(kt + 1) * 32 * 256;
      const ushort_t* vn = vbb + (kt + 1) * 32;
      const int nb2 = cur ^ 1;
#pragma unroll
      for (int i = 0; i < 4; ++i) {
        const int i2 = wv * 4 + i;
        dma16(kn + (size_t)l32 * 256 + (i2 * 2 + hw) * 8, &kld[nb2][i2 * 512]);
        dma16(vn + (size_t)(i * 64 + lane) * 2048 + wv * 8, &vld[nb2][(wv * 256 + i * 64) * 8]);
      }
    }
    // QK^T (16x16x32): S[32q x 32k] per wave as 2mf x 2s frags; B shared by mf
    f4 sc[2][2];
#pragma unroll
    for (int mf = 0; mf < 2; ++mf)
#pragma unroll
      for (int s = 0; s < 2; ++s) sc[mf][s] = (f4){0.f, 0.f, 0.f, 0.f};
#pragma unroll
    for (int c = 0; c < 8; ++c) {
      const s8 qa0 = *(const s8*)(qrow0 + c * 32);   // L1/L2-resident reload
      const s8 qa1 = *(const s8*)(qrow1 + c * 32);
#pragma unroll
      for (int s = 0; s < 2; ++s) {
        const s8 bfr = *(const s8*)&kld[cur][((c * 4 + quad) * 32 + s * 16 + l16) * 8];
        sc[0][s] = __builtin_amdgcn_mfma_f32_16x16x32_bf16(qa0, bfr, sc[0][s], 0, 0, 0);
        sc[1][s] = __builtin_amdgcn_mfma_f32_16x16x32_bf16(qa1, bfr, sc[1][s], 0, 0, 0);
      }
    }
    // exp (no max-shift), per-lane l partials, weights -> pl
#pragma unroll
    for (int s = 0; s < 2; ++s) {
      const int m = m0 + s * 16 + l16;
      const float2 cc = ((const float2*)coords)[b * 2048 + m];
      const float mfv = mask[b * 2048 + m] ? 0.f : 1.f;
#pragma unroll
      for (int mf = 0; mf < 2; ++mf)
#pragma unroll
        for (int r = 0; r < 4; ++r) {
          const float p = __expf(sc[mf][s][r]);
          lrun[mf][r] += p;
          const float dx = rcx[mf][r] - cc.x, dy = rcy[mf][r] - cc.y;
          const float dist = sqrtf(fmaxf(dx * dx + dy * dy, 0.f));
          const float w = p * __expf(-gamma * dist) * mfv;
          pl[(wv * 32 + mf * 16 + quad * 4 + r) * 40 + s * 16 + l16] = (short)f2bf(w);
        }
    }
    // PV (32x32x16): O[32q x 256d] += P[32q x 32k] * V[32k x 256d]
    const s8 pa0 = *(const s8*)&pl[(wv * 32 + l32) * 40 + hw * 8];
    const s8 pa1 = *(const s8*)&pl[(wv * 32 + l32) * 40 + 16 + hw * 8];
#pragma unroll
    for (int dt = 0; dt < 8; ++dt) {
      const s8 bv0 = *(const s8*)&vld[cur][(hw * 256 + dt * 32 + l32) * 8];
      o32[dt] = __builtin_amdgcn_mfma_f32_32x32x16_bf16(pa0, bv0, o32[dt], 0, 0, 0);
      const s8 bv1 = *(const s8*)&vld[cur][((2 + hw) * 256 + dt * 32 + l32) * 8];
      o32[dt] = __builtin_amdgcn_mfma_f32_32x32x16_bf16(pa1, bv1, o32[dt], 0, 0, 0);
    }
    __syncthreads();
  }
  // epilogue: partial O (unnormalized, bf16) via 32x32 C-layout
  ushort_t* OpK = Opb + (size_t)ks * 4194304;
#pragma unroll
  for (int dt = 0; dt < 8; ++dt) {
#pragma unroll
    for (int reg = 0; reg < 16; ++reg) {
      const int row = (reg & 3) + 8 * (reg >> 2) + 4 * hw;
      OpK[((size_t)b * 2048 + qw + row) * 256 + dt * 32 + l32] = f2bf(o32[dt][reg]);
    }
  }
  // l: single end-of-kernel reduction over the 16 l16 lanes
#pragma unroll
  for (int o2 = 1; o2 < 16; o2 <<= 1) {
#pragma unroll
    for (int mf = 0; mf < 2; ++mf)
#pragma unroll
      for (int r = 0; r < 4; ++r) lrun[mf][r] += __shfl_xor(lrun[mf][r], o2);
  }
  if (l16 == 0) {
#pragma unroll
    for (int mf = 0; mf < 2; ++mf)
#pragma unroll
      for (int r = 0; r < 4; ++r)
        lws[ks * 16384 + b * 2048 + qw + mf * 16 + quad * 4 + r] = lrun[mf][r];
  }
}

// ---- BN GEMM + LN + ReLU + FUSED masked pool (atomicAdd) ----
// obn is never written: out rows only feed the masked mean-pool.
__global__ __launch_bounds__(256, 3) void k_gemm_bn(
    const ushort_t* __restrict__ Opb, const float* __restrict__ lws,
    const ushort_t* __restrict__ WT,
    const float* __restrict__ bia, const float* __restrict__ g,
    const float* __restrict__ beta, float* __restrict__ pooledAcc) {
  __shared__ short Al[32 * 72];
  __shared__ short Bl[128 * 72];
  __shared__ float red1[32][2], red2[32][2];
  __shared__ float sCm[32];
  const int t = threadIdx.x;
  const int wv = t >> 6, lane = t & 63, l16 = lane & 15, quad = lane >> 4;
  const int wm = wv >> 1, wn = wv & 1;
  const int row0 = blockIdx.x * 32;
  const int b = row0 >> 11;

  if (t < 32) {
    const int row = row0 + t;
    sCm[t] = 1.f / (lws[row] + lws[16384 + row] + lws[32768 + row] + lws[49152 + row]);
  }

  f4 acc[4];
#pragma unroll
  for (int nf = 0; nf < 4; ++nf) acc[nf] = (f4){0.f, 0.f, 0.f, 0.f};

  for (int k0 = 0; k0 < 256; k0 += 64) {
    __syncthreads();
    {   // stage A: sum 4 bf16 partials, scale, repack bf16
      const int r = t >> 3, c8 = t & 7;
      const float c0 = sCm[r];
      const size_t off = (size_t)(row0 + r) * 256 + k0 + c8 * 8;
      float e[8];
#pragma unroll
      for (int j = 0; j < 8; ++j) e[j] = 0.f;
#pragma unroll
      for (int pp = 0; pp < 4; ++pp) {
        const uint4 u = *(const uint4*)&Opb[(size_t)pp * 4194304 + off];
        e[0] += bf2f((ushort_t)(u.x & 0xffff)); e[1] += bf2f((ushort_t)(u.x >> 16));
        e[2] += bf2f((ushort_t)(u.y & 0xffff)); e[3] += bf2f((ushort_t)(u.y >> 16));
        e[4] += bf2f((ushort_t)(u.z & 0xffff)); e[5] += bf2f((ushort_t)(u.z >> 16));
        e[6] += bf2f((ushort_t)(u.w & 0xffff)); e[7] += bf2f((ushort_t)(u.w >> 16));
      }
      float4 ea = {c0 * e[0], c0 * e[1], c0 * e[2], c0 * e[3]};
      float4 eb = {c0 * e[4], c0 * e[5], c0 * e[6], c0 * e[7]};
      *(uint4*)&Al[r * 72 + c8 * 8] = pack8(ea, eb);
    }
#pragma unroll
    for (int i = 0; i < 4; ++i) {
      const int ch = t + i * 256;
      const int r = ch >> 3, c8 = ch & 7;
      *(uint4*)&Bl[r * 72 + c8 * 8] =
          *(const uint4*)&WT[(size_t)r * 256 + k0 + c8 * 8];
    }
    __syncthreads();
#pragma unroll
    for (int kc = 0; kc < 2; ++kc) {
      const s8 af = *(const s8*)&Al[(wm * 16 + l16) * 72 + kc * 32 + quad * 8];
#pragma unroll
      for (int nf = 0; nf < 4; ++nf) {
        const s8 bf = *(const s8*)&Bl[(wn * 64 + nf * 16 + l16) * 72 + kc * 32 + quad * 8];
        acc[nf] = __builtin_amdgcn_mfma_f32_16x16x32_bf16(af, bf, acc[nf], 0, 0, 0);
      }
    }
  }
  float bi[4], gg[4], bb[4];
#pragma unroll
  for (int nf = 0; nf < 4; ++nf) {
    const int col = wn * 64 + nf * 16 + l16;
    bi[nf] = bia[col]; gg[nf] = g[col]; bb[nf] = beta[col];
  }
  float s1[4] = {0.f, 0.f, 0.f, 0.f}, s2[4] = {0.f, 0.f, 0.f, 0.f};
#pragma unroll
  for (int nf = 0; nf < 4; ++nf)
#pragma unroll
    for (int r = 0; r < 4; ++r) {
      const float v = acc[nf][r] + bi[nf];
      acc[nf][r] = v;
      s1[r] += v; s2[r] += v * v;
    }
#pragma unroll
  for (int m = 1; m < 16; m <<= 1) {
#pragma unroll
    for (int r = 0; r < 4; ++r) {
      s1[r] += __shfl_xor(s1[r], m);
      s2[r] += __shfl_xor(s2[r], m);
    }
  }
  if (l16 == 0) {
#pragma unroll
    for (int r = 0; r < 4; ++r) {
      const int rl = wm * 16 + quad * 4 + r;
      red1[rl][wn] = s1[r]; red2[rl][wn] = s2[r];
    }
  }
  __syncthreads();
  // LN + ReLU + masked row-sum (in registers), then atomics
  float colsum[4] = {0.f, 0.f, 0.f, 0.f};
  const int* mrow = (const int*)0;
#pragma unroll
  for (int r = 0; r < 4; ++r) {
    const int rl = wm * 16 + quad * 4 + r;
    const float mu = (red1[rl][0] + red1[rl][1]) * (1.f / 128.f);
    const float var = (red2[rl][0] + red2[rl][1]) * (1.f / 128.f) - mu * mu;
    const float rstd = rsqrtf(var + 1e-5f);
    // mask weight for this row (n = row0+rl, batch-local)
    extern const int* __mask_dummy;  // (unused; placeholder removed below)
#pragma unroll
    for (int nf = 0; nf < 4; ++nf) {
      const float v = (acc[nf][r] - mu) * rstd * gg[nf] + bb[nf];
      acc[nf][r] = fmaxf(v, 0.f);
    }
  }
  (void)mrow;
  // apply row mask and sum over the 4 rows this lane owns
  {
    float mw[4];
#pragma unroll
    for (int r = 0; r < 4; ++r) {
      const int rl = wm * 16 + quad * 4 + r;
      mw[r] = pooledAcc[1024 + row0 + rl] ;  // mask staged as float by k_maskf
    }
#pragma unroll
    for (int nf = 0; nf < 4; ++nf) {
      float s = acc[nf][0] * mw[0] + acc[nf][1] * mw[1] +
                acc[nf][2] * mw[2] + acc[nf][3] * mw[3];
      // reduce across quads (rows): lanes quad 0..3 same l16
      s += __shfl_xor(s, 16);
      s += __shfl_xor(s, 32);
      if (quad == 0) {
        const int col = wn * 64 + nf * 16 + l16;
        atomicAdd(&pooledAcc[b * 128 + col], s);
      }
    }
  }
}

// ---- stage mask as float weights (1=keep) into pooledAcc[1024..17408) ----
__global__ __launch_bounds__(256) void k_maskf(const int* __restrict__ mask,
                                               float* __restrict__ pooledAcc) {
  const int i = blockIdx.x * 256 + threadIdx.x;
  if (i < 16384) pooledAcc[1024 + i] = mask[i] ? 0.f : 1.f;
  if (i < 1024) pooledAcc[i] = 0.f;   // zero the accumulators (no memset needed)
}

// ---------------- fused pool finalize + MLP head ----------------
__global__ __launch_bounds__(128) void k_pool2_head(
    const float* __restrict__ pooledAcc, const int* __restrict__ mask,
    const float* __restrict__ c1w, const float* __restrict__ c1b,
    const float* __restrict__ c2w, const float* __restrict__ c2b,
    float* __restrict__ dout) {
  __shared__ float ps[128];
  __shared__ float h1[64];
  __shared__ float scnt[128];
  const int b = blockIdx.x, t = threadIdx.x;
  // count unmasked rows
  float c = 0.f;
  const int* mb = mask + b * 2048 + t * 16;
#pragma unroll
  for (int j = 0; j < 16; ++j) c += mb[j] ? 0.f : 1.f;
  scnt[t] = c;
  __syncthreads();
  for (int o2 = 64; o2 > 0; o2 >>= 1) {
    if (t < o2) scnt[t] += scnt[t + o2];
    __syncthreads();
  }
  const float cnt = scnt[0];
  const float p = pooledAcc[b * 128 + t] / fmaxf(cnt, 1e-9f);
  ps[t] = p;
  dout[80 + b * 128 + t] = p;
  __syncthreads();
  if (t < 64) {
    float acc = c1b[t];
    for (int d = 0; d < 128; ++d) acc += ps[d] * c1w[d * 64 + t];
    h1[t] = fmaxf(acc, 0.f);
  }
  __syncthreads();
  if (t < 10) {
    float a2 = c2b[t];
    for (int j = 0; j < 64; ++j) a2 += h1[j] * c2w[j * 10 + t];
    dout[b * 10 + t] = a2;
  }
}

extern "C" void kernel_launch(void* const* d_in, const int* in_sizes, int n_in,
                              void* d_out, int out_size, void* d_ws, size_t ws_size,
                              hipStream_t stream) {
  const float* lf     = (const float*)d_in[0];
  const float* coords = (const float*)d_in[1];
  const int*   mask   = (const int*)d_in[2];
  const float* enc_w  = (const float*)d_in[3];
  const float* enc_b  = (const float*)d_in[4];
  const float* enc_g  = (const float*)d_in[5];
  const float* enc_be = (const float*)d_in[6];
  const float* gamma  = (const float*)d_in[7];
  const float* wq     = (const float*)d_in[8];
  const float* bq     = (const float*)d_in[9];
  const float* wk     = (const float*)d_in[10];
  const float* bk     = (const float*)d_in[11];
  const float* wv     = (const float*)d_in[12];
  const float* bv     = (const float*)d_in[13];
  const float* bn_w   = (const float*)d_in[14];
  const float* bn_b   = (const float*)d_in[15];
  const float* bn_g   = (const float*)d_in[16];
  const float* bn_be  = (const float*)d_in[17];
  const float* c1w    = (const float*)d_in[18];
  const float* c1b    = (const float*)d_in[19];
  const float* c2w    = (const float*)d_in[20];
  const float* c2b    = (const float*)d_in[21];

  // ws layout (float units), ~73 MB (as R9) + pooledAcc block:
  //  [0,2M) h_bf | [2M,4M) q_bf | [4M,6M) k_bf | [6M,8M) vt_bf
  //  [8M,16M) Op bf16, 4 partials x 4194304 ushorts
  //  [16.8M..) enc_wT | wqkvT | bn_wT | lws(4x16K) | pooledAcc(1024)+maskf(16384)
  float* ws = (float*)d_ws;
  ushort_t* h_bf   = (ushort_t*)ws;
  ushort_t* q_bf   = (ushort_t*)(ws + 2097152);
  ushort_t* k_bf   = (ushort_t*)(ws + 4194304);
  ushort_t* vt_bf  = (ushort_t*)(ws + 6291456);
  ushort_t* Opb    = (ushort_t*)(ws + 8388608);    // 4 x 4194304 ushorts
  ushort_t* enc_wT = (ushort_t*)(ws + 17825792);
  ushort_t* wqkvT  = (ushort_t*)(ws + 17891328);
  ushort_t* bn_wT  = (ushort_t*)(ws + 17989632);
  float*    lws    = ws + 18006016;                // 4 x 16384
  float*    pooledAcc = ws + 18071552;             // [0,1024) sums; [1024,17408) maskf
  float* out = (float*)d_out;

  k_wt_all<<<dim3(512, 5), 256, 0, stream>>>(enc_w, wq, wk, wv, bn_w,
                                             enc_wT, wqkvT, bn_wT);
  k_maskf<<<64, 256, 0, stream>>>(mask, pooledAcc);
  k_gemm_enc<<<512, 256, 0, stream>>>(lf, enc_wT, enc_b, enc_g, enc_be, h_bf);
  k_gemm_qkv<<<dim3(256, 6), 256, 0, stream>>>(h_bf, wqkvT, bq, bk, bv, q_bf, k_bf, vt_bf);
  k_attn<<<dim3(16, 4, 8), 256, 0, stream>>>(q_bf, k_bf, vt_bf, coords, mask, gamma,
                                             Opb, lws);
  k_gemm_bn<<<512, 256, 0, stream>>>(Opb, lws, bn_wT, bn_b, bn_g, bn_be, pooledAcc);
  k_pool2_head<<<8, 128, 0, stream>>>(pooledAcc, mask, c1w, c1b, c2w, c2b, out);
}